// Round 1
// baseline (1183.539 us; speedup 1.0000x reference)
//
#include <hip/hip_runtime.h>
#include <hip/hip_bf16.h>

// SpiralFC: out[b,o,y,x] = sum_c W[o,c] * x[b, y+dy[c], x+dx[c], c] + bias[o]
// Offsets are integer-valued floats (round() in reference) -> bilinear weights
// degenerate to a pure integer shift with zero padding.
//
// GEMM view: out^T[o][m] = W[o][k] * Xs[m][k], m = global pixel (b*3136+y*56+x)
//   A operand = W   (M'=512 outputs), staged [o][k] in LDS (bf16)
//   B operand = Xs  (N'=100352 pixels), staged [m][k] in LDS (bf16, gathered)
// MFMA 16x16x32 bf16; block tile 128(o) x 128(m) x BK=64; 4 waves, each 64x64.

#define HD 56
#define WD 56
#define HW 3136
#define CCH 512
#define NBATCH 32

#define BM 128          // outputs per block
#define BN 128          // pixels per block
#define BK 64
#define LDK 72          // BK + 8 pad (16B) -> 2-way-max bank aliasing (free)

typedef __attribute__((ext_vector_type(8))) __bf16 bf16x8;
typedef __attribute__((ext_vector_type(4))) float f32x4;

__device__ __forceinline__ unsigned short f2bf(float f) {
    __hip_bfloat16 h = __float2bfloat16(f);
    return __builtin_bit_cast(unsigned short, h);
}

__global__ __launch_bounds__(256) void spiralfc_kernel(
    const float* __restrict__ x,     // [B][H][W][C]
    const float* __restrict__ wgt,   // [O][C]
    const float* __restrict__ bias,  // [O]
    const float* __restrict__ offs,  // [C][2] (dy, dx) integer-valued
    float* __restrict__ out)         // [B][O][H][W]
{
    __shared__ unsigned short sW[BM * LDK];
    __shared__ unsigned short sX[BN * LDK];
    __shared__ int sDy[CCH];
    __shared__ int sDx[CCH];
    __shared__ float sBias[BM];

    const int tid = threadIdx.x;
    const int bid = blockIdx.x;
    const int ot = bid & 3;          // 4 o-tiles
    const int pt = bid >> 2;         // 784 pixel-tiles
    const int O0 = ot * BM;
    const int P0 = pt * BN;

    // Preload per-channel integer offsets + bias slice
    for (int k = tid; k < CCH; k += 256) {
        sDy[k] = (int)offs[2 * k];
        sDx[k] = (int)offs[2 * k + 1];
    }
    if (tid < BM) sBias[tid] = bias[O0 + tid];

    const int w   = tid >> 6;   // wave 0..3
    const int l   = tid & 63;
    const int q   = l >> 4;     // quad
    const int c16 = l & 15;

    const int wo = w & 1;       // wave o-offset (x64)
    const int wm = w >> 1;      // wave m-offset (x64)

    f32x4 acc[4][4];
#pragma unroll
    for (int i = 0; i < 4; i++)
#pragma unroll
        for (int j = 0; j < 4; j++) acc[i][j] = (f32x4)0.0f;

    const int kcW = tid & 15;   // weight k-chunk (4 floats)
    const int orW = tid >> 4;   // weight row within pass

    __syncthreads();

    for (int kk = 0; kk < CCH; kk += BK) {
        // ---- stage weight tile [BM][BK], fp32 -> bf16 (weight is L2-resident)
#pragma unroll
        for (int ps = 0; ps < 8; ps++) {
            const int o = ps * 16 + orW;
            const float4 wv = *(const float4*)(wgt + (size_t)(O0 + o) * CCH + kk + kcW * 4);
            ushort4 uv;
            uv.x = f2bf(wv.x); uv.y = f2bf(wv.y); uv.z = f2bf(wv.z); uv.w = f2bf(wv.w);
            *(ushort4*)&sW[o * LDK + kcW * 4] = uv;
        }

        // ---- stage shifted-x tile [BN][BK]: lanes sweep k (mostly-contiguous
        //      gather runs; channels 256..511 have zero shift -> fully coalesced)
#pragma unroll 4
        for (int ps = 0; ps < 32; ps++) {
            const int m = ps * 4 + w;          // wave-uniform row
            const int g = P0 + m;
            const int b = g / HW;
            const int p = g - b * HW;
            const int y = p / WD;
            const int xx = p - y * WD;
            const int k = kk + l;
            const int yy = y + sDy[k];
            const int xs = xx + sDx[k];
            float v = 0.0f;
            if ((unsigned)yy < (unsigned)HD && (unsigned)xs < (unsigned)WD) {
                v = x[((size_t)b * HW + yy * WD + xs) * CCH + k];
            }
            sX[m * LDK + l] = f2bf(v);
        }
        __syncthreads();

        // ---- MFMA: 2 k-slices of 32; each wave 4x4 grid of 16x16 tiles
#pragma unroll
        for (int s = 0; s < 2; s++) {
            bf16x8 af[4], bf[4];
#pragma unroll
            for (int i = 0; i < 4; i++) {
                const int o_l = wo * 64 + i * 16 + c16;
                af[i] = *(const bf16x8*)&sW[o_l * LDK + s * 32 + q * 8];
            }
#pragma unroll
            for (int j = 0; j < 4; j++) {
                const int m_l = wm * 64 + j * 16 + c16;
                bf[j] = *(const bf16x8*)&sX[m_l * LDK + s * 32 + q * 8];
            }
#pragma unroll
            for (int i = 0; i < 4; i++)
#pragma unroll
                for (int j = 0; j < 4; j++)
                    acc[i][j] = __builtin_amdgcn_mfma_f32_16x16x32_bf16(
                        af[i], bf[j], acc[i][j], 0, 0, 0);
        }
        __syncthreads();
    }

    // ---- epilogue: D[row=o_sub=q*4+r][col=m_sub=c16]; lanes 0..15 sweep
    //      consecutive pixels -> coalesced 64B stores per quad
#pragma unroll
    for (int j = 0; j < 4; j++) {
        const int g = P0 + wm * 64 + j * 16 + c16;
        const int b = g / HW;
        const int p = g - b * HW;
        float* obase = out + (size_t)b * CCH * HW + p;
#pragma unroll
        for (int i = 0; i < 4; i++) {
#pragma unroll
            for (int r = 0; r < 4; r++) {
                const int o_l = wo * 64 + i * 16 + q * 4 + r;
                obase[(size_t)(O0 + o_l) * HW] = acc[i][j][r] + sBias[o_l];
            }
        }
    }
}

extern "C" void kernel_launch(void* const* d_in, const int* in_sizes, int n_in,
                              void* d_out, int out_size, void* d_ws, size_t ws_size,
                              hipStream_t stream) {
    const float* x    = (const float*)d_in[0];
    const float* wgt  = (const float*)d_in[1];
    const float* bias = (const float*)d_in[2];
    const float* offs = (const float*)d_in[3];
    float* out = (float*)d_out;

    // 784 pixel-tiles * 4 o-tiles
    spiralfc_kernel<<<dim3(3136), dim3(256), 0, stream>>>(x, wgt, bias, offs, out);
}

// Round 2
// 555.142 us; speedup vs baseline: 2.1320x; 2.1320x over previous
//
#include <hip/hip_runtime.h>
#include <hip/hip_bf16.h>

// SpiralFC: out[b,o,y,x] = sum_c W[o,c] * x[b, y+dy[c], x+dx[c], c] + bias[o]
// Integer shifts (round() in reference) -> pure shift with zero padding.
//
// Two-phase plan:
//   K1 shift_kernel : Xs[m][c] = bf16(x[b, y+dy[c], x+dx[c], c])  (ws)
//                     + Wb[o][c] = bf16(W[o][c])                  (ws)
//   K2 gemm_kernel  : out^T[o][m] = Wb[o][:] . Xs[m][:] + bias[o]
//      128(o) x 128(m) x BK=64, mfma 16x16x32 bf16,
//      global_load_lds width=16 staging, XOR k-chunk swizzle (conflict-free).

#define HD 56
#define WD 56
#define HW 3136
#define CCH 512
#define NBATCH 32
#define MTOT (NBATCH * HW)          // 100352

#define BM 128
#define BN 128
#define BK 64

#define XS_ELEMS ((size_t)MTOT * CCH)
#define XS_BYTES (XS_ELEMS * 2)            // 102,760,448
#define WB_BYTES ((size_t)CCH * CCH * 2)   // 524,288

typedef __attribute__((ext_vector_type(8))) __bf16 bf16x8;
typedef __attribute__((ext_vector_type(4))) float f32x4;
typedef __attribute__((ext_vector_type(8))) unsigned short ushort8_t;

#define AS1 __attribute__((address_space(1)))
#define AS3 __attribute__((address_space(3)))

__device__ __forceinline__ unsigned short f2bf(float f) {
    __hip_bfloat16 h = __float2bfloat16(f);
    return __builtin_bit_cast(unsigned short, h);
}

__device__ __forceinline__ void load16_lds(const unsigned short* g, unsigned short* l) {
    __builtin_amdgcn_global_load_lds((const AS1 unsigned int*)g,
                                     (AS3 unsigned int*)l, 16, 0, 0);
}

// ---------------------------------------------------------------- K1: shift
#define PIX_BLOCKS (MTOT * (CCH / 8) / 256)   // 25088
#define WGT_BLOCKS (CCH * CCH / 8 / 256)      // 128

__global__ __launch_bounds__(256) void shift_kernel(
    const float* __restrict__ x,     // [B][H][W][C]
    const float* __restrict__ wgt,   // [O][C]
    const float* __restrict__ offs,  // [C][2]
    unsigned short* __restrict__ Xs, // [M][C] bf16
    unsigned short* __restrict__ Wb) // [O][C] bf16
{
    const int tid = threadIdx.x;

    if (blockIdx.x >= PIX_BLOCKS) {
        // weight convert: 8 floats / thread
        const int e = (blockIdx.x - PIX_BLOCKS) * 256 + tid;
        const float4* src = (const float4*)wgt + (size_t)e * 2;
        float4 a = src[0], b = src[1];
        ushort8_t o;
        o[0] = f2bf(a.x); o[1] = f2bf(a.y); o[2] = f2bf(a.z); o[3] = f2bf(a.w);
        o[4] = f2bf(b.x); o[5] = f2bf(b.y); o[6] = f2bf(b.z); o[7] = f2bf(b.w);
        *(ushort8_t*)(Wb + (size_t)e * 8) = o;
        return;
    }

    __shared__ int cDy[CCH], cDx[CCH];
    __shared__ int sDy[64], sDx[64], sUni[64];

    for (int k = tid; k < CCH; k += 256) {
        cDy[k] = (int)offs[2 * k];
        cDx[k] = (int)offs[2 * k + 1];
    }
    __syncthreads();
    if (tid < 64) {
        const int c0 = tid * 8;
        int dy = cDy[c0], dx = cDx[c0], u = 1;
#pragma unroll
        for (int j = 1; j < 8; j++)
            u &= (cDy[c0 + j] == dy) & (cDx[c0 + j] == dx);
        sDy[tid] = dy; sDx[tid] = dx; sUni[tid] = u;
    }
    __syncthreads();

    const int e = blockIdx.x * 256 + tid;  // chunk of 8 channels
    const int m = e >> 6;
    const int cq = e & 63;
    const int c0 = cq * 8;
    const int b = m / HW;
    const int p = m - b * HW;
    const int y = p / WD;
    const int xx = p - y * WD;

    ushort8_t o = (ushort8_t)0;
    if (sUni[cq]) {
        const int yy = y + sDy[cq];
        const int xs = xx + sDx[cq];
        if ((unsigned)yy < (unsigned)HD && (unsigned)xs < (unsigned)WD) {
            const float4* s = (const float4*)(x + ((size_t)b * HW + yy * WD + xs) * CCH + c0);
            float4 a = s[0], bb = s[1];
            o[0] = f2bf(a.x);  o[1] = f2bf(a.y);  o[2] = f2bf(a.z);  o[3] = f2bf(a.w);
            o[4] = f2bf(bb.x); o[5] = f2bf(bb.y); o[6] = f2bf(bb.z); o[7] = f2bf(bb.w);
        }
    } else {
#pragma unroll
        for (int j = 0; j < 8; j++) {
            const int c = c0 + j;
            const int yy = y + cDy[c];
            const int xs = xx + cDx[c];
            float v = 0.0f;
            if ((unsigned)yy < (unsigned)HD && (unsigned)xs < (unsigned)WD)
                v = x[((size_t)b * HW + yy * WD + xs) * CCH + c];
            o[j] = f2bf(v);
        }
    }
    *(ushort8_t*)(Xs + (size_t)m * CCH + c0) = o;
}

// ----------------------------------------------------------------- K2: GEMM
__global__ __launch_bounds__(256) void gemm_kernel(
    const unsigned short* __restrict__ Xs,   // [M][512] bf16
    const unsigned short* __restrict__ Wb,   // [512][512] bf16
    const float* __restrict__ bias,
    float* __restrict__ out)                 // [B][O][H][W]
{
    __shared__ unsigned short sW[BM * BK];   // 16KB, no pad (global_load_lds)
    __shared__ unsigned short sX[BN * BK];   // 16KB
    __shared__ float sBias[BM];

    const int tid = threadIdx.x;
    const int bid = blockIdx.x;
    const int ot = bid & 3;
    const int pt = bid >> 2;
    const int O0 = ot * BM;
    const int P0 = pt * BN;

    if (tid < BM) sBias[tid] = bias[O0 + tid];

    const int w   = tid >> 6;
    const int l   = tid & 63;
    const int q   = l >> 4;
    const int c16 = l & 15;
    const int wo  = w & 1;
    const int wm  = w >> 1;

    // XOR swizzle: lds chunk (row, slot) holds global k-chunk slot^(row&7)
    const int lc    = (l & 7) ^ ((l >> 3) & 7);   // staging gather chunk
    const int k7    = c16 & 7;
    const int slot0 = q ^ k7;                     // frag slot, s=0 (chunk q)
    const int slot1 = (4 + q) ^ k7;               // frag slot, s=1 (chunk 4+q)

    f32x4 acc[4][4];
#pragma unroll
    for (int i = 0; i < 4; i++)
#pragma unroll
        for (int j = 0; j < 4; j++) acc[i][j] = (f32x4)0.0f;

    for (int kk = 0; kk < CCH; kk += BK) {
        // stage both tiles: 4+4 wave-issues of 16B/lane direct-to-LDS
#pragma unroll
        for (int i = 0; i < 4; i++) {
            const int ib = w * 4 + i;            // 1KB LDS chunk index
            const int row = ib * 8 + (l >> 3);
            const unsigned short* gW = Wb + (size_t)(O0 + row) * CCH + kk + lc * 8;
            const unsigned short* gX = Xs + (size_t)(P0 + row) * CCH + kk + lc * 8;
            load16_lds(gW, &sW[ib * 512]);
            load16_lds(gX, &sX[ib * 512]);
        }
        __syncthreads();

#pragma unroll
        for (int s = 0; s < 2; s++) {
            const int slot = s ? slot1 : slot0;
            bf16x8 af[4], bf[4];
#pragma unroll
            for (int i = 0; i < 4; i++) {
                const int row = wo * 64 + i * 16 + c16;
                af[i] = *(const bf16x8*)&sW[row * BK + slot * 8];
            }
#pragma unroll
            for (int j = 0; j < 4; j++) {
                const int row = wm * 64 + j * 16 + c16;
                bf[j] = *(const bf16x8*)&sX[row * BK + slot * 8];
            }
#pragma unroll
            for (int i = 0; i < 4; i++)
#pragma unroll
                for (int j = 0; j < 4; j++)
                    acc[i][j] = __builtin_amdgcn_mfma_f32_16x16x32_bf16(
                        af[i], bf[j], acc[i][j], 0, 0, 0);
        }
        __syncthreads();
    }

    // epilogue: D[row=q*4+r][col=c16]; lanes 0..15 sweep consecutive pixels
#pragma unroll
    for (int j = 0; j < 4; j++) {
        const int g = P0 + wm * 64 + j * 16 + c16;
        const int b = g / HW;
        const int p = g - b * HW;
        float* obase = out + (size_t)b * CCH * HW + p;
#pragma unroll
        for (int i = 0; i < 4; i++) {
#pragma unroll
            for (int r = 0; r < 4; r++) {
                const int o_l = wo * 64 + i * 16 + q * 4 + r;
                obase[(size_t)(O0 + o_l) * HW] = acc[i][j][r] + sBias[o_l];
            }
        }
    }
}

// ------------------------------------------------------- fallback (fused R1)
#define LDK 72
__global__ __launch_bounds__(256) void spiralfc_fused(
    const float* __restrict__ x, const float* __restrict__ wgt,
    const float* __restrict__ bias, const float* __restrict__ offs,
    float* __restrict__ out)
{
    __shared__ unsigned short sW[BM * LDK];
    __shared__ unsigned short sX[BN * LDK];
    __shared__ int sDy[CCH];
    __shared__ int sDx[CCH];
    __shared__ float sBias[BM];

    const int tid = threadIdx.x;
    const int bid = blockIdx.x;
    const int O0 = (bid & 3) * BM;
    const int P0 = (bid >> 2) * BN;

    for (int k = tid; k < CCH; k += 256) {
        sDy[k] = (int)offs[2 * k];
        sDx[k] = (int)offs[2 * k + 1];
    }
    if (tid < BM) sBias[tid] = bias[O0 + tid];

    const int w = tid >> 6, l = tid & 63, q = l >> 4, c16 = l & 15;
    const int wo = w & 1, wm = w >> 1;

    f32x4 acc[4][4];
#pragma unroll
    for (int i = 0; i < 4; i++)
#pragma unroll
        for (int j = 0; j < 4; j++) acc[i][j] = (f32x4)0.0f;

    const int kcW = tid & 15, orW = tid >> 4;
    __syncthreads();

    for (int kk = 0; kk < CCH; kk += BK) {
#pragma unroll
        for (int ps = 0; ps < 8; ps++) {
            const int o = ps * 16 + orW;
            const float4 wv = *(const float4*)(wgt + (size_t)(O0 + o) * CCH + kk + kcW * 4);
            ushort4 uv;
            uv.x = f2bf(wv.x); uv.y = f2bf(wv.y); uv.z = f2bf(wv.z); uv.w = f2bf(wv.w);
            *(ushort4*)&sW[o * LDK + kcW * 4] = uv;
        }
#pragma unroll 4
        for (int ps = 0; ps < 32; ps++) {
            const int m = ps * 4 + w;
            const int g = P0 + m;
            const int b = g / HW;
            const int p = g - b * HW;
            const int y = p / WD;
            const int xx = p - y * WD;
            const int k = kk + l;
            const int yy = y + sDy[k];
            const int xs = xx + sDx[k];
            float v = 0.0f;
            if ((unsigned)yy < (unsigned)HD && (unsigned)xs < (unsigned)WD)
                v = x[((size_t)b * HW + yy * WD + xs) * CCH + k];
            sX[m * LDK + l] = f2bf(v);
        }
        __syncthreads();
#pragma unroll
        for (int s = 0; s < 2; s++) {
            bf16x8 af[4], bf[4];
#pragma unroll
            for (int i = 0; i < 4; i++)
                af[i] = *(const bf16x8*)&sW[(wo * 64 + i * 16 + c16) * LDK + s * 32 + q * 8];
#pragma unroll
            for (int j = 0; j < 4; j++)
                bf[j] = *(const bf16x8*)&sX[(wm * 64 + j * 16 + c16) * LDK + s * 32 + q * 8];
#pragma unroll
            for (int i = 0; i < 4; i++)
#pragma unroll
                for (int j = 0; j < 4; j++)
                    acc[i][j] = __builtin_amdgcn_mfma_f32_16x16x32_bf16(
                        af[i], bf[j], acc[i][j], 0, 0, 0);
        }
        __syncthreads();
    }
#pragma unroll
    for (int j = 0; j < 4; j++) {
        const int g = P0 + wm * 64 + j * 16 + c16;
        const int b = g / HW;
        const int p = g - b * HW;
        float* obase = out + (size_t)b * CCH * HW + p;
#pragma unroll
        for (int i = 0; i < 4; i++)
#pragma unroll
            for (int r = 0; r < 4; r++) {
                const int o_l = wo * 64 + i * 16 + q * 4 + r;
                obase[(size_t)(O0 + o_l) * HW] = acc[i][j][r] + sBias[o_l];
            }
    }
}

extern "C" void kernel_launch(void* const* d_in, const int* in_sizes, int n_in,
                              void* d_out, int out_size, void* d_ws, size_t ws_size,
                              hipStream_t stream) {
    const float* x    = (const float*)d_in[0];
    const float* wgt  = (const float*)d_in[1];
    const float* bias = (const float*)d_in[2];
    const float* offs = (const float*)d_in[3];
    float* out = (float*)d_out;

    if (ws_size >= XS_BYTES + WB_BYTES) {
        unsigned short* Xs = (unsigned short*)d_ws;
        unsigned short* Wb = (unsigned short*)((char*)d_ws + XS_BYTES);
        shift_kernel<<<dim3(PIX_BLOCKS + WGT_BLOCKS), dim3(256), 0, stream>>>(
            x, wgt, offs, Xs, Wb);
        gemm_kernel<<<dim3(3136), dim3(256), 0, stream>>>(Xs, Wb, bias, out);
    } else {
        spiralfc_fused<<<dim3(3136), dim3(256), 0, stream>>>(x, wgt, bias, offs, out);
    }
}